// Round 2
// baseline (382.237 us; speedup 1.0000x reference)
//
#include <hip/hip_runtime.h>
#include <type_traits>

#define NBATCH 32
#define NDIM 512
#define NFAST 448

// ---- DPP cross-lane primitives (VALU-speed; no LDS, no barriers) ----

template <int CTRL, int RMASK>
__device__ __forceinline__ float dpp_add(float x) {
  int t = __builtin_amdgcn_update_dpp(0, __float_as_int(x), CTRL, RMASK, 0xf,
                                      false);
  return x + __int_as_float(t);
}

// wave64 inclusive prefix sum
__device__ __forceinline__ float prefix_inc(float x) {
  x = dpp_add<0x111, 0xf>(x);  // row_shr:1
  x = dpp_add<0x112, 0xf>(x);  // row_shr:2
  x = dpp_add<0x114, 0xf>(x);  // row_shr:4
  x = dpp_add<0x118, 0xf>(x);  // row_shr:8
  x = dpp_add<0x142, 0xa>(x);  // row_bcast:15 -> rows 1,3
  x = dpp_add<0x143, 0xc>(x);  // row_bcast:31 -> rows 2,3
  return x;
}

// shift one lane up (lane i gets lane i-1); lane 0 receives `fill`
__device__ __forceinline__ float wave_shr1(float x, float fill) {
  return __int_as_float(__builtin_amdgcn_update_dpp(
      __float_as_int(fill), __float_as_int(x), 0x138 /*wave_shr:1*/, 0xf, 0xf,
      false));
}

// one step of the wave64 inclusive affine-composition scan.
// Compose earlier-then-later: B = A*Be + B ; A = A*Ae. Identity = (1,0).
template <int CTRL, int RMASK>
__device__ __forceinline__ void aff_step(float& A, float& B) {
  float Ae = __int_as_float(__builtin_amdgcn_update_dpp(
      __float_as_int(1.0f), __float_as_int(A), CTRL, RMASK, 0xf, false));
  float Be = __int_as_float(__builtin_amdgcn_update_dpp(
      0, __float_as_int(B), CTRL, RMASK, 0xf, false));
  B = fmaf(A, Be, B);
  A = A * Ae;
}

// Workgroup barrier WITHOUT the vmcnt(0) drain __syncthreads() emits.
__device__ __forceinline__ void wg_barrier() {
  asm volatile("s_waitcnt lgkmcnt(0)" ::: "memory");
  __builtin_amdgcn_s_barrier();
  asm volatile("" ::: "memory");
}

// Validate a prefetched record: spin-reload until its seq field == m.
// Records are write-once; writer orders data-before-seq with lgkmcnt(0),
// so any read-tear (<= few cycles spread) cannot pair fresh seq with
// stale data (writer's data->seq gap is an LDS write round trip, ~20+ cy).
__device__ __forceinline__ float4 lds_wait_rec(float4 r, const float4* p,
                                               int m) {
  while (__builtin_expect(__float_as_int(r.w) != m, 0)) {
    __builtin_amdgcn_s_sleep(1);
    asm volatile("" ::: "memory");  // force a fresh ds_read_b128
    r = *p;
  }
  return r;
}

// R15: barrier-free wave pipeline on FAST rows. One workgroup (4 waves)
// per batch element; wave w owns columns [128w, 128w+128), lane owns 2.
// FAST rows (0..447) have strictly forward cross-wave deps, so waves run
// as a producer/consumer pipeline: each wave publishes a write-once
// {A,B,PA,seq} record per row; consumers prefetch next-row records at the
// end of each row and validate via seq. No barriers, no exposed LDS
// latency on the chain. FULL rows (448..511) have a backward dep (future
// mass), and keep the R14 2-barrier body; the first barrier there
// re-syncs the pipeline skew automatically.
__global__ __launch_bounds__(256, 1)
void sb_kernel(const float* __restrict__ x, const float* __restrict__ xm,
               float* __restrict__ out) {
  const int tid = (int)threadIdx.x;
  const int lane = tid & 63;
  const int w = __builtin_amdgcn_readfirstlane(tid >> 6);  // wave id 0..3
  const size_t base =
      (size_t)blockIdx.x * NDIM * NDIM + (size_t)(w * 128 + lane * 2);
  const float* xb = x + base;
  const float* mb = xm + base;
  float* ob = out + base;

  __shared__ float4 recs[NFAST][4];       // 28 KB, write-once row records
  __shared__ alignas(16) float ex_sa[4];  // FULL-mode barrier exchange
  __shared__ alignas(16) float ex_S[4];
  __shared__ alignas(16) float ex_A[4];
  __shared__ alignas(16) float ex_B[4];

  // per-lane state for the 2 owned columns
  float w8_0, w8_1, t8_0, t8_1, pre1, sa;
  float fu0 = 0.0f, fu1 = 0.0f, suf0 = 0.0f, S = 0.0f;
  float wp0, wp1, sp0 = 0.0f, sp1 = 0.0f;
  float c1_0 = 0.0f, c1_1 = 0.0f, c2_0, c2_1, oc2_0, oc2_1;

  // 4 global prefetch slots, one row each (issued before LDS init so they
  // stay in flight across the lgkm-only init barrier)
  float2 x0, m0, x1, m1, x2, m2, x3, m3;
  x0 = *(const float2*)(xb);
  m0 = *(const float2*)(mb);
  x1 = *(const float2*)(xb + NDIM);
  m1 = *(const float2*)(mb + NDIM);
  x2 = *(const float2*)(xb + 2 * NDIM);
  m2 = *(const float2*)(mb + 2 * NDIM);
  x3 = *(const float2*)(xb + 3 * NDIM);
  m3 = *(const float2*)(mb + 3 * NDIM);

  // init record seq fields to -1 (LDS content is undefined at start)
  for (int i = tid; i < NFAST * 4; i += 256)
    recs[i >> 2][i & 3].w = __int_as_float(-1);
  wg_barrier();

  auto build_pre = [&]() {
    pre1 = t8_0;
    sa = t8_0 + t8_1;
    wp0 = w8_0;         // w8 + pre(=0)
    wp1 = w8_1 + pre1;  // w8 + pre
  };
  auto build_suf = [&]() {
    suf0 = fu1;  // suf[1] = 0
    S = fu0 + fu1;
    sp0 = suf0;  // suf + pre(=0)
    sp1 = pre1;  // suf(=0) + pre
  };

  {  // row-0 prep: constants + scan inputs (w == 1, cs == 0)
    float s0 = __builtin_amdgcn_rcpf(1.0f + __expf(-x0.x));
    float s1 = __builtin_amdgcn_rcpf(1.0f + __expf(-x0.y));
    c2_0 = m0.x * s0;
    c2_1 = m0.y * s1;
    oc2_0 = 1.0f - c2_0;
    oc2_1 = 1.0f - c2_1;
    w8_0 = 1.0f;
    w8_1 = 1.0f;
    t8_0 = c2_0;
    t8_1 = c2_1;
    build_pre();
  }

  // prefetched predecessor records (loop-carried)
  float4 pr0 = make_float4(0.f, 0.f, 0.f, __int_as_float(-1));
  float4 pr1 = pr0, pr2 = pr0;
  if (w > 0) pr0 = recs[0][0];
  if (w > 1) pr1 = recs[0][1];
  if (w > 2) pr2 = recs[0][2];

  // ---- FAST row body: barrier-free pipelined ----
  auto row_fast = [&](auto MODEC, int m, float2& WX, float2& WM,
                      const float2& RX, const float2& RM) {
    constexpr int MODE = decltype(MODEC)::value;  // 0 or 1
    const size_t nro = (size_t)((m + 4) & (NDIM - 1)) * NDIM;
    WX = *(const float2*)(xb + nro);
    WM = *(const float2*)(mb + nro);

    // ---- local prefix scan (chain head) ----
    float PA = prefix_inc(sa);

    // ---- consume predecessors' row-m records (prefetched last row) ----
    float off_sa = 0.0f;
    float E = 1.0f;  // row entry into this wave
    if (w > 0) {
      pr0 = lds_wait_rec(pr0, &recs[m][0], m);
      off_sa += pr0.z;
      E = fmaf(pr0.x, E, pr0.y);
    }
    if (w > 1) {
      pr1 = lds_wait_rec(pr1, &recs[m][1], m);
      off_sa += pr1.z;
      E = fmaf(pr1.x, E, pr1.y);
    }
    if (w > 2) {
      pr2 = lds_wait_rec(pr2, &recs[m][2], m);
      off_sa += pr2.z;
      E = fmaf(pr2.x, E, pr2.y);
    }

    // linear entry guess: 1 - (global exclusive t8-prefix before this lane)
    float uin = fmaxf(1.0f - (off_sa + (PA - sa)), 0.0f);

    // ---- parallel branch prediction (2 cells) ----
    bool pW0 = wp0 < uin;
    bool pW1 = wp1 < uin;
    float aP0 = pW0 ? 1.0f : oc2_0;
    float aP1 = pW1 ? 1.0f : oc2_1;
    float bP0 = pW0 ? (-t8_0) : 0.0f;
    float bP1 = pW1 ? (-t8_1) : 0.0f;

    // ---- pair compose + wave affine scan ----
    float A = aP1 * aP0;
    float Bv = fmaf(aP1, bP0, bP1);
    aff_step<0x111, 0xf>(A, Bv);
    aff_step<0x112, 0xf>(A, Bv);
    aff_step<0x114, 0xf>(A, Bv);
    aff_step<0x118, 0xf>(A, Bv);
    aff_step<0x142, 0xa>(A, Bv);
    aff_step<0x143, 0xc>(A, Bv);
    float Aex = wave_shr1(A, 1.0f);
    float Bex = wave_shr1(Bv, 0.0f);

    // ---- publish own record (write-once; data before seq) ----
    if (w < 3 && lane == 63) {
      float4* rp = &recs[m][w];
      rp->x = A;
      rp->y = Bv;
      rp->z = PA;
      asm volatile("s_waitcnt lgkmcnt(0)" ::: "memory");
      *(volatile int*)&rp->w = m;
    }

    float e = fminf(fmaxf(fmaf(Aex, E, Bex), 0.0f), 1.0f);  // lane entry

    // ---- row m+1 x-only prep (data loaded 3+ rows ago; off-chain) ----
    float c1n0 = 0.0f, c1n1 = 0.0f, c2n0, c2n1, oc2n0, oc2n1;
    {
      float s0 = __builtin_amdgcn_rcpf(1.0f + __expf(-RX.x));
      float s1 = __builtin_amdgcn_rcpf(1.0f + __expf(-RX.y));
      c2n0 = RM.x * s0;
      c2n1 = RM.y * s1;
      oc2n0 = 1.0f - c2n0;
      oc2n1 = 1.0f - c2n1;
      if constexpr (MODE >= 1) {
        c1n0 = RM.x - c2n0;
        c1n1 = RM.y - c2n1;
      }
    }

    // ---- within-lane entries + TRUE-branch outputs (g==0 on fast rows) --
    float uu0 = e;
    float uu1 = fmaxf(fmaf(aP0, e, bP0), 0.0f);
    float U0 = fminf(uu0, w8_0);
    float U1 = fminf(uu1, w8_1);
    float p0 = c2_0 * U0;
    float p1 = c2_1 * U1;
    w8_0 -= p0;
    w8_1 -= p1;
    *(float2*)(ob + (size_t)m * NDIM) = make_float2(p0, p1);

    // ---- next row's scan inputs (the real cross-row chain) ----
    t8_0 = c2n0 * w8_0;
    t8_1 = c2n1 * w8_1;
    build_pre();
    c2_0 = c2n0;
    c2_1 = c2n1;
    oc2_0 = oc2n0;
    oc2_1 = oc2n1;
    if constexpr (MODE >= 1) {
      c1_0 = c1n0;
      c1_1 = c1n1;
    }

    // ---- prefetch next fast row's records (validated next iteration) ----
    if (m + 1 < NFAST) {
      asm volatile("" ::: "memory");
      if (w > 0) pr0 = recs[m + 1][0];
      if (w > 1) pr1 = recs[m + 1][1];
      if (w > 2) pr2 = recs[m + 1][2];
    }
  };

  // ---- FULL row body: R14 2-barrier structure (backward dep on S) ----
  auto row_full = [&](int m, float2& WX, float2& WM, const float2& RX,
                      const float2& RM) {
    const size_t nro = (size_t)((m + 4) & (NDIM - 1)) * NDIM;
    WX = *(const float2*)(xb + nro);
    WM = *(const float2*)(mb + nro);

    // ---- local wave scans (chain head) ----
    float PS = prefix_inc(S);
    float PA = prefix_inc(sa);

    if (lane == 63) {
      ex_sa[w] = PA;  // wave-inclusive total
      ex_S[w] = PS;
    }
    wg_barrier();  // bar1: publish scan totals

    float4 sav = *(const float4*)ex_sa;
    float off_sa = 0.0f;
    if (w > 0) off_sa += sav.x;
    if (w > 1) off_sa += sav.y;
    if (w > 2) off_sa += sav.z;
    float uin = fmaxf(1.0f - (off_sa + (PA - sa)), 0.0f);

    float4 Sv = *(const float4*)ex_S;
    float Tg = (Sv.x + Sv.y) + (Sv.z + Sv.w);
    float off_S = 0.0f;
    if (w > 0) off_S += Sv.x;
    if (w > 1) off_S += Sv.y;
    if (w > 2) off_S += Sv.z;
    float R_ = (Tg - off_S) - PS;  // future mass strictly after this lane
    float mfm0 = R_ + suf0;
    float mfm1 = R_;  // suf[1] = 0
    float nc1m0 = -c1_0 * mfm0;
    float nc1m1 = -c1_1 * mfm1;

    // ---- parallel branch prediction (2 cells) ----
    bool pW0 = wp0 < uin;
    bool pW1 = wp1 < uin;
    float aP0 = pW0 ? 1.0f : oc2_0;
    float aP1 = pW1 ? 1.0f : oc2_1;
    float bP0 = pW0 ? (-t8_0) : 0.0f;
    float bP1 = pW1 ? (-t8_1) : 0.0f;
    float d = uin - R_;
    bool pL0 = d > sp0;
    bool pL1 = d > sp1;
    if (pL0) {
      aP0 -= c1_0;
      bP0 -= nc1m0;
    }
    if (pL1) {
      aP1 -= c1_1;
      bP1 -= nc1m1;
    }

    // ---- pair compose + wave affine scan ----
    float A = aP1 * aP0;
    float Bv = fmaf(aP1, bP0, bP1);
    aff_step<0x111, 0xf>(A, Bv);
    aff_step<0x112, 0xf>(A, Bv);
    aff_step<0x114, 0xf>(A, Bv);
    aff_step<0x118, 0xf>(A, Bv);
    aff_step<0x142, 0xa>(A, Bv);
    aff_step<0x143, 0xc>(A, Bv);
    float Aex = wave_shr1(A, 1.0f);
    float Bex = wave_shr1(Bv, 0.0f);

    if (lane == 63) {
      ex_A[w] = A;  // wave-inclusive composition
      ex_B[w] = Bv;
    }
    wg_barrier();  // bar2: publish affine totals

    float4 eAv = *(const float4*)ex_A;
    float4 eBv = *(const float4*)ex_B;
    float E = 1.0f;
    if (w > 0) E = fmaf(eAv.x, E, eBv.x);
    if (w > 1) E = fmaf(eAv.y, E, eBv.y);
    if (w > 2) E = fmaf(eAv.z, E, eBv.z);
    float e = fminf(fmaxf(fmaf(Aex, E, Bex), 0.0f), 1.0f);  // lane entry

    // ---- row m+1 x-only prep ----
    float c1n0, c1n1, c2n0, c2n1, oc2n0, oc2n1, omn0, omn1;
    {
      float s0 = __builtin_amdgcn_rcpf(1.0f + __expf(-RX.x));
      float s1 = __builtin_amdgcn_rcpf(1.0f + __expf(-RX.y));
      c2n0 = RM.x * s0;
      c2n1 = RM.y * s1;
      oc2n0 = 1.0f - c2n0;
      oc2n1 = 1.0f - c2n1;
      c1n0 = RM.x - c2n0;
      c1n1 = RM.y - c2n1;
      omn0 = 1.0f - RM.x;
      omn1 = 1.0f - RM.y;
    }

    // ---- within-lane entries + TRUE-branch outputs ----
    float uu0 = e;
    float uu1 = fmaxf(fmaf(aP0, e, bP0), 0.0f);
    float U0 = fminf(uu0, w8_0);
    float U1 = fminf(uu1, w8_1);
    float g0 = fmaxf(fmaf(c1_0, uu0, nc1m0), 0.0f);
    float g1 = fmaxf(fmaf(c1_1, uu1, nc1m1), 0.0f);
    float p0 = fmaf(c2_0, U0, g0);
    float p1 = fmaf(c2_1, U1, g1);
    w8_0 -= p0;
    w8_1 -= p1;
    *(float2*)(ob + (size_t)m * NDIM) = make_float2(p0, p1);

    // ---- next row's scan inputs ----
    t8_0 = c2n0 * w8_0;
    t8_1 = c2n1 * w8_1;
    build_pre();
    fu0 = fmaxf(w8_0 - omn0, 0.0f);
    fu1 = fmaxf(w8_1 - omn1, 0.0f);
    build_suf();
    c2_0 = c2n0;
    c2_1 = c2n1;
    oc2_0 = oc2n0;
    oc2_1 = oc2n1;
    c1_0 = c1n0;
    c1_1 = c1n1;
  };

  using Fast0 = std::integral_constant<int, 0>;
  using Fast1 = std::integral_constant<int, 1>;

#pragma unroll 1
  for (int m = 0; m < 444; m += 4) {
    row_fast(Fast0{}, m + 0, x0, m0, x1, m1);
    row_fast(Fast0{}, m + 1, x1, m1, x2, m2);
    row_fast(Fast0{}, m + 2, x2, m2, x3, m3);
    row_fast(Fast0{}, m + 3, x3, m3, x0, m0);
  }
  // last fast group: also carries c1 forward for the bridge
  row_fast(Fast1{}, 444, x0, m0, x1, m1);
  row_fast(Fast1{}, 445, x1, m1, x2, m2);
  row_fast(Fast1{}, 446, x2, m2, x3, m3);
  row_fast(Fast1{}, 447, x3, m3, x0, m0);

  // bridge: rebuild fu/S/suf/sp for row 448 (om = 1 - mask = 1 - (c1+c2))
  {
    float om0 = 1.0f - c1_0 - c2_0;
    float om1 = 1.0f - c1_1 - c2_1;
    fu0 = fmaxf(w8_0 - om0, 0.0f);
    fu1 = fmaxf(w8_1 - om1, 0.0f);
    build_suf();
  }

#pragma unroll 1
  for (int m = 448; m < NDIM; m += 4) {
    row_full(m + 0, x0, m0, x1, m1);
    row_full(m + 1, x1, m1, x2, m2);
    row_full(m + 2, x2, m2, x3, m3);
    row_full(m + 3, x3, m3, x0, m0);
  }
}

extern "C" void kernel_launch(void* const* d_in, const int* in_sizes, int n_in,
                              void* d_out, int out_size, void* d_ws,
                              size_t ws_size, hipStream_t stream) {
  const float* x = (const float*)d_in[0];
  const float* xmask = (const float*)d_in[1];
  float* out = (float*)d_out;
  (void)in_sizes;
  (void)n_in;
  (void)out_size;
  (void)d_ws;
  (void)ws_size;
  hipLaunchKernelGGL(sb_kernel, dim3(NBATCH), dim3(256), 0, stream, x, xmask,
                     out);
}

// Round 3
// 299.355 us; speedup vs baseline: 1.2769x; 1.2769x over previous
//
#include <hip/hip_runtime.h>
#include <type_traits>

#define NBATCH 32
#define NDIM 512
#define NFAST 448

// ---- DPP cross-lane primitives (VALU-speed; no LDS, no barriers) ----

template <int CTRL, int RMASK>
__device__ __forceinline__ float dpp_add(float x) {
  int t = __builtin_amdgcn_update_dpp(0, __float_as_int(x), CTRL, RMASK, 0xf,
                                      false);
  return x + __int_as_float(t);
}

// wave64 inclusive prefix sum
__device__ __forceinline__ float prefix_inc(float x) {
  x = dpp_add<0x111, 0xf>(x);  // row_shr:1
  x = dpp_add<0x112, 0xf>(x);  // row_shr:2
  x = dpp_add<0x114, 0xf>(x);  // row_shr:4
  x = dpp_add<0x118, 0xf>(x);  // row_shr:8
  x = dpp_add<0x142, 0xa>(x);  // row_bcast:15 -> rows 1,3
  x = dpp_add<0x143, 0xc>(x);  // row_bcast:31 -> rows 2,3
  return x;
}

// shift one lane up (lane i gets lane i-1); lane 0 receives `fill`
__device__ __forceinline__ float wave_shr1(float x, float fill) {
  return __int_as_float(__builtin_amdgcn_update_dpp(
      __float_as_int(fill), __float_as_int(x), 0x138 /*wave_shr:1*/, 0xf, 0xf,
      false));
}

// one step of the wave64 inclusive affine-composition scan.
// Compose earlier-then-later: B = A*Be + B ; A = A*Ae. Identity = (1,0).
template <int CTRL, int RMASK>
__device__ __forceinline__ void aff_step(float& A, float& B) {
  float Ae = __int_as_float(__builtin_amdgcn_update_dpp(
      __float_as_int(1.0f), __float_as_int(A), CTRL, RMASK, 0xf, false));
  float Be = __int_as_float(__builtin_amdgcn_update_dpp(
      0, __float_as_int(B), CTRL, RMASK, 0xf, false));
  B = fmaf(A, Be, B);
  A = A * Ae;
}

// Workgroup barrier WITHOUT the vmcnt(0) drain __syncthreads() emits.
// Writer-side LDS ordering via lgkmcnt(0); trailing empty asm with a
// memory clobber stops the compiler hoisting post-barrier LDS reads.
// Global prefetch loads stay in flight across step barriers.
__device__ __forceinline__ void wg_barrier() {
  asm volatile("s_waitcnt lgkmcnt(0)" ::: "memory");
  __builtin_amdgcn_s_barrier();
  asm volatile("" ::: "memory");
}

// R16: systolic skew. Wave w processes row m at step t = m + w, one
// barrier per step. All cross-wave inputs for row m (predecessor waves'
// {A, B, PA} records) were published at steps m+w' < t, so they are
// guaranteed present in LDS after the step-start barrier — no same-step
// exchange, no spin/validate, record-read latency hidden behind the
// local prefix scan + sigmoid prep. Per-step critical path is one
// wave's LOCAL row work (~400 cy) vs R14's 1090 (2 same-row barrier
// round-trips). FULL rows (448..511) have a backward (suffix-sum) dep
// that a forward skew cannot satisfy; they keep the R14 2-barrier body
// after a de-skew bridge. Fast-row arithmetic is bit-identical to R14
// (same off_sa order, same stepwise E chain, same pieces).
__global__ __launch_bounds__(256, 1)
void sb_kernel(const float* __restrict__ x, const float* __restrict__ xm,
               float* __restrict__ out) {
  const int tid = (int)threadIdx.x;
  const int lane = tid & 63;
  const int w = __builtin_amdgcn_readfirstlane(tid >> 6);  // wave id 0..3
  const size_t base =
      (size_t)blockIdx.x * NDIM * NDIM + (size_t)(w * 128 + lane * 2);
  const float* xb = x + base;
  const float* mb = xm + base;
  float* ob = out + base;

  __shared__ float4 recs[NFAST][3];       // 21 KB write-once {A,B,PA} records
  __shared__ alignas(16) float ex_sa[4];  // FULL-mode barrier exchange
  __shared__ alignas(16) float ex_S[4];
  __shared__ alignas(16) float ex_A[4];
  __shared__ alignas(16) float ex_B[4];

  // per-lane state for the 2 owned columns
  float w8_0, w8_1, t8_0, t8_1, pre1, sa;
  float fu0 = 0.0f, fu1 = 0.0f, suf0 = 0.0f, S = 0.0f;
  float wp0, wp1, sp0 = 0.0f, sp1 = 0.0f;
  float c1_0, c1_1, c2_0, c2_1, oc2_0, oc2_1;

  // ---- initial loads: row 0 direct; rows 1..3 into t-indexed slots ----
  // Slot discipline: at step t (unrolled position r = t&3) a wave loads
  // row m+4 into slot r and prep-consumes row m+1 from slot (r+1)&3.
  // Both indices depend only on t, so the unroll stays compile-time even
  // though m = t - w is wave-dependent. Initial fill: row r0 lands in
  // slot (w+r0)&3.
  float2 X0 = *(const float2*)(xb);
  float2 M0 = *(const float2*)(mb);
  float2 a1 = *(const float2*)(xb + NDIM), b1 = *(const float2*)(mb + NDIM);
  float2 a2 = *(const float2*)(xb + 2 * NDIM),
         b2 = *(const float2*)(mb + 2 * NDIM);
  float2 a3 = *(const float2*)(xb + 3 * NDIM),
         b3 = *(const float2*)(mb + 3 * NDIM);
  float2 sx0 = a1, sm0 = b1, sx1 = a1, sm1 = b1, sx2 = a1, sm2 = b1, sx3 = a1,
         sm3 = b1;
  switch (w) {
    case 0:
      sx1 = a1; sm1 = b1; sx2 = a2; sm2 = b2; sx3 = a3; sm3 = b3;
      break;
    case 1:
      sx2 = a1; sm2 = b1; sx3 = a2; sm3 = b2; sx0 = a3; sm0 = b3;
      break;
    case 2:
      sx3 = a1; sm3 = b1; sx0 = a2; sm0 = b2; sx1 = a3; sm1 = b3;
      break;
    default:
      sx0 = a1; sm0 = b1; sx1 = a2; sm1 = b2; sx2 = a3; sm2 = b3;
      break;
  }

  auto build_pre = [&]() {
    pre1 = t8_0;
    sa = t8_0 + t8_1;
    wp0 = w8_0;         // w8 + pre(=0)
    wp1 = w8_1 + pre1;  // w8 + pre
  };
  auto build_suf = [&]() {
    suf0 = fu1;  // suf[1] = 0
    S = fu0 + fu1;
    sp0 = suf0;  // suf + pre(=0)
    sp1 = pre1;  // suf(=0) + pre
  };

  {  // row-0 prep: constants + scan inputs (w == 1, cs == 0)
    float s0 = __builtin_amdgcn_rcpf(1.0f + __expf(-X0.x));
    float s1 = __builtin_amdgcn_rcpf(1.0f + __expf(-X0.y));
    c2_0 = M0.x * s0;
    c2_1 = M0.y * s1;
    oc2_0 = 1.0f - c2_0;
    oc2_1 = 1.0f - c2_1;
    c1_0 = M0.x - c2_0;
    c1_1 = M0.y - c2_1;
    w8_0 = 1.0f;
    w8_1 = 1.0f;
    t8_0 = c2_0;
    t8_1 = c2_1;
    build_pre();
  }

  // ---- systolic fast step: one barrier, no same-step exchange ----
  auto fast_step = [&](int t, float2& LXx, float2& LXm, const float2& CXx,
                       const float2& CXm) {
    const int m = t - w;
    if ((unsigned)m < (unsigned)NFAST) {  // wave-uniform
      // issue predecessor record reads (published >=1 step ago)
      float4 r0, r1, r2;
      if (w > 0) r0 = recs[m][0];
      if (w > 1) r1 = recs[m][1];
      if (w > 2) r2 = recs[m][2];
      // issue next-row global load (m+4 <= 451, no wrap needed)
      const size_t nro = (size_t)(m + 4) * NDIM;
      LXx = *(const float2*)(xb + nro);
      LXm = *(const float2*)(mb + nro);

      // local prefix scan (chain head; covers record-read latency)
      float PA = prefix_inc(sa);

      // row m+1 x-only prep (data loaded 4 steps ago; off-chain, also
      // covers record-read latency)
      float sg0 = __builtin_amdgcn_rcpf(1.0f + __expf(-CXx.x));
      float sg1 = __builtin_amdgcn_rcpf(1.0f + __expf(-CXx.y));
      float c2n0 = CXm.x * sg0;
      float c2n1 = CXm.y * sg1;
      float oc2n0 = 1.0f - c2n0;
      float oc2n1 = 1.0f - c2n1;
      float c1n0 = CXm.x - c2n0;
      float c1n1 = CXm.y - c2n1;

      // cross-wave inputs (same summation/composition order as R14)
      float off_sa = 0.0f;
      float E = 1.0f;
      if (w > 0) {
        off_sa += r0.z;
        E = fmaf(r0.x, E, r0.y);
      }
      if (w > 1) {
        off_sa += r1.z;
        E = fmaf(r1.x, E, r1.y);
      }
      if (w > 2) {
        off_sa += r2.z;
        E = fmaf(r2.x, E, r2.y);
      }
      float uin = fmaxf(1.0f - (off_sa + (PA - sa)), 0.0f);

      // parallel branch prediction (2 cells)
      bool pW0 = wp0 < uin;
      bool pW1 = wp1 < uin;
      float aP0 = pW0 ? 1.0f : oc2_0;
      float aP1 = pW1 ? 1.0f : oc2_1;
      float bP0 = pW0 ? (-t8_0) : 0.0f;
      float bP1 = pW1 ? (-t8_1) : 0.0f;

      // pair compose + wave affine scan
      float A = aP1 * aP0;
      float Bv = fmaf(aP1, bP0, bP1);
      aff_step<0x111, 0xf>(A, Bv);
      aff_step<0x112, 0xf>(A, Bv);
      aff_step<0x114, 0xf>(A, Bv);
      aff_step<0x118, 0xf>(A, Bv);
      aff_step<0x142, 0xa>(A, Bv);
      aff_step<0x143, 0xc>(A, Bv);
      float Aex = wave_shr1(A, 1.0f);
      float Bex = wave_shr1(Bv, 0.0f);

      // publish own record for successors (consumed next step; the
      // wg_barrier's lgkmcnt(0) orders it before the barrier)
      if (w < 3 && lane == 63) recs[m][w] = make_float4(A, Bv, PA, 0.0f);

      float e = fminf(fmaxf(fmaf(Aex, E, Bex), 0.0f), 1.0f);  // lane entry

      // within-lane entries + TRUE-branch outputs (g==0 on fast rows)
      float uu0 = e;
      float uu1 = fmaxf(fmaf(aP0, e, bP0), 0.0f);
      float U0 = fminf(uu0, w8_0);
      float U1 = fminf(uu1, w8_1);
      float p0 = c2_0 * U0;
      float p1 = c2_1 * U1;
      w8_0 -= p0;
      w8_1 -= p1;
      *(float2*)(ob + (size_t)m * NDIM) = make_float2(p0, p1);

      // next row's scan inputs (the real cross-row chain)
      t8_0 = c2n0 * w8_0;
      t8_1 = c2n1 * w8_1;
      build_pre();
      c2_0 = c2n0;
      c2_1 = c2n1;
      oc2_0 = oc2n0;
      oc2_1 = oc2n1;
      c1_0 = c1n0;
      c1_1 = c1n1;
    }
    wg_barrier();
  };

  // fast phase: steps t = 0 .. 451 (wave w active for t in [w, w+448))
#pragma unroll 1
  for (int t = 0; t < NFAST + 4; t += 4) {
    fast_step(t + 0, sx0, sm0, sx1, sm1);
    fast_step(t + 1, sx1, sm1, sx2, sm2);
    fast_step(t + 2, sx2, sm2, sx3, sm3);
    fast_step(t + 3, sx3, sm3, sx0, sm0);
  }

  // ---- bridge: de-skewed; rebuild fu/S/suf/sp for row 448 and reload
  // rows 449..451 into canonical slots (L2-hot, one-time) ----
  sx1 = *(const float2*)(xb + (size_t)449 * NDIM);
  sm1 = *(const float2*)(mb + (size_t)449 * NDIM);
  sx2 = *(const float2*)(xb + (size_t)450 * NDIM);
  sm2 = *(const float2*)(mb + (size_t)450 * NDIM);
  sx3 = *(const float2*)(xb + (size_t)451 * NDIM);
  sm3 = *(const float2*)(mb + (size_t)451 * NDIM);
  {
    float om0 = 1.0f - c1_0 - c2_0;
    float om1 = 1.0f - c1_1 - c2_1;
    fu0 = fmaxf(w8_0 - om0, 0.0f);
    fu1 = fmaxf(w8_1 - om1, 0.0f);
    build_suf();
  }

  // ---- FULL row body: R14 2-barrier structure (backward dep on S) ----
  auto row_full = [&](int m, float2& WX, float2& WM, const float2& RX,
                      const float2& RM) {
    const size_t nro = (size_t)((m + 4) & (NDIM - 1)) * NDIM;
    WX = *(const float2*)(xb + nro);
    WM = *(const float2*)(mb + nro);

    // local wave scans (chain head)
    float PS = prefix_inc(S);
    float PA = prefix_inc(sa);

    if (lane == 63) {
      ex_sa[w] = PA;  // wave-inclusive total
      ex_S[w] = PS;
    }
    wg_barrier();  // bar1: publish scan totals

    float4 sav = *(const float4*)ex_sa;
    float off_sa = 0.0f;
    if (w > 0) off_sa += sav.x;
    if (w > 1) off_sa += sav.y;
    if (w > 2) off_sa += sav.z;
    float uin = fmaxf(1.0f - (off_sa + (PA - sa)), 0.0f);

    float4 Sv = *(const float4*)ex_S;
    float Tg = (Sv.x + Sv.y) + (Sv.z + Sv.w);
    float off_S = 0.0f;
    if (w > 0) off_S += Sv.x;
    if (w > 1) off_S += Sv.y;
    if (w > 2) off_S += Sv.z;
    float R_ = (Tg - off_S) - PS;  // future mass strictly after this lane
    float mfm0 = R_ + suf0;
    float mfm1 = R_;  // suf[1] = 0
    float nc1m0 = -c1_0 * mfm0;
    float nc1m1 = -c1_1 * mfm1;

    // parallel branch prediction (2 cells)
    bool pW0 = wp0 < uin;
    bool pW1 = wp1 < uin;
    float aP0 = pW0 ? 1.0f : oc2_0;
    float aP1 = pW1 ? 1.0f : oc2_1;
    float bP0 = pW0 ? (-t8_0) : 0.0f;
    float bP1 = pW1 ? (-t8_1) : 0.0f;
    float d = uin - R_;
    bool pL0 = d > sp0;
    bool pL1 = d > sp1;
    if (pL0) {
      aP0 -= c1_0;
      bP0 -= nc1m0;
    }
    if (pL1) {
      aP1 -= c1_1;
      bP1 -= nc1m1;
    }

    // pair compose + wave affine scan
    float A = aP1 * aP0;
    float Bv = fmaf(aP1, bP0, bP1);
    aff_step<0x111, 0xf>(A, Bv);
    aff_step<0x112, 0xf>(A, Bv);
    aff_step<0x114, 0xf>(A, Bv);
    aff_step<0x118, 0xf>(A, Bv);
    aff_step<0x142, 0xa>(A, Bv);
    aff_step<0x143, 0xc>(A, Bv);
    float Aex = wave_shr1(A, 1.0f);
    float Bex = wave_shr1(Bv, 0.0f);

    if (lane == 63) {
      ex_A[w] = A;  // wave-inclusive composition
      ex_B[w] = Bv;
    }
    wg_barrier();  // bar2: publish affine totals

    float4 eAv = *(const float4*)ex_A;
    float4 eBv = *(const float4*)ex_B;
    float E = 1.0f;
    if (w > 0) E = fmaf(eAv.x, E, eBv.x);
    if (w > 1) E = fmaf(eAv.y, E, eBv.y);
    if (w > 2) E = fmaf(eAv.z, E, eBv.z);
    float e = fminf(fmaxf(fmaf(Aex, E, Bex), 0.0f), 1.0f);  // lane entry

    // row m+1 x-only prep
    float c1n0, c1n1, c2n0, c2n1, oc2n0, oc2n1, omn0, omn1;
    {
      float s0 = __builtin_amdgcn_rcpf(1.0f + __expf(-RX.x));
      float s1 = __builtin_amdgcn_rcpf(1.0f + __expf(-RX.y));
      c2n0 = RM.x * s0;
      c2n1 = RM.y * s1;
      oc2n0 = 1.0f - c2n0;
      oc2n1 = 1.0f - c2n1;
      c1n0 = RM.x - c2n0;
      c1n1 = RM.y - c2n1;
      omn0 = 1.0f - RM.x;
      omn1 = 1.0f - RM.y;
    }

    // within-lane entries + TRUE-branch outputs
    float uu0 = e;
    float uu1 = fmaxf(fmaf(aP0, e, bP0), 0.0f);
    float U0 = fminf(uu0, w8_0);
    float U1 = fminf(uu1, w8_1);
    float g0 = fmaxf(fmaf(c1_0, uu0, nc1m0), 0.0f);
    float g1 = fmaxf(fmaf(c1_1, uu1, nc1m1), 0.0f);
    float p0 = fmaf(c2_0, U0, g0);
    float p1 = fmaf(c2_1, U1, g1);
    w8_0 -= p0;
    w8_1 -= p1;
    *(float2*)(ob + (size_t)m * NDIM) = make_float2(p0, p1);

    // next row's scan inputs
    t8_0 = c2n0 * w8_0;
    t8_1 = c2n1 * w8_1;
    build_pre();
    fu0 = fmaxf(w8_0 - omn0, 0.0f);
    fu1 = fmaxf(w8_1 - omn1, 0.0f);
    build_suf();
    c2_0 = c2n0;
    c2_1 = c2n1;
    oc2_0 = oc2n0;
    oc2_1 = oc2n1;
    c1_0 = c1n0;
    c1_1 = c1n1;
  };

#pragma unroll 1
  for (int m = NFAST; m < NDIM; m += 4) {
    row_full(m + 0, sx0, sm0, sx1, sm1);
    row_full(m + 1, sx1, sm1, sx2, sm2);
    row_full(m + 2, sx2, sm2, sx3, sm3);
    row_full(m + 3, sx3, sm3, sx0, sm0);
  }
}

extern "C" void kernel_launch(void* const* d_in, const int* in_sizes, int n_in,
                              void* d_out, int out_size, void* d_ws,
                              size_t ws_size, hipStream_t stream) {
  const float* x = (const float*)d_in[0];
  const float* xmask = (const float*)d_in[1];
  float* out = (float*)d_out;
  (void)in_sizes;
  (void)n_in;
  (void)out_size;
  (void)d_ws;
  (void)ws_size;
  hipLaunchKernelGGL(sb_kernel, dim3(NBATCH), dim3(256), 0, stream, x, xmask,
                     out);
}